// Round 13
// baseline (237.895 us; speedup 1.0000x reference)
//
#include <hip/hip_runtime.h>

typedef unsigned short ushort_t;
typedef unsigned int uint32;
typedef __attribute__((ext_vector_type(8))) short short8;
typedef __attribute__((ext_vector_type(4))) float float4v;
typedef __attribute__((ext_vector_type(4))) unsigned short ushort4v;

#define NEG_INF (-__builtin_inff())

__device__ __forceinline__ ushort_t f2bf(float f) {
  uint32 u = __float_as_uint(f);
  u += 0x7fffu + ((u >> 16) & 1u);
  return (ushort_t)(u >> 16);
}

__device__ __forceinline__ short8 cvt8(float4v u0, float4v u1) {
  short8 sv;
  sv[0] = (short)f2bf(u0.x);
  sv[1] = (short)f2bf(u0.y);
  sv[2] = (short)f2bf(u0.z);
  sv[3] = (short)f2bf(u0.w);
  sv[4] = (short)f2bf(u1.x);
  sv[5] = (short)f2bf(u1.y);
  sv[6] = (short)f2bf(u1.z);
  sv[7] = (short)f2bf(u1.w);
  return sv;
}

__device__ __forceinline__ void glds16(const void* g, void* l) {
  __builtin_amdgcn_global_load_lds(
      (__attribute__((address_space(1))) const void*)g,
      (__attribute__((address_space(3))) void*)l, 16, 0, 0);
}

// ---------------- batched f32 -> bf16 weight conversion ----------------
struct CvtW {
  const float* in[4];
  ushort_t* out[4];
};

__global__ __launch_bounds__(256) void cvt_w_kernel(CvtW a) {
  const float* in = a.in[blockIdx.y];
  ushort_t* out = a.out[blockIdx.y];
  int i = blockIdx.x * 256 + threadIdx.x;
  float4v v = ((const float4v*)in)[i];
  ushort4v o;
  o.x = f2bf(v.x);
  o.y = f2bf(v.y);
  o.z = f2bf(v.z);
  o.w = f2bf(v.w);
  ((ushort4v*)out)[i] = o;
}

// ---------------- projection GEMM: C_bf16 = cvt(A_f32) * B_bf16^T ----------
// 128x128 tile, BK=32, 4 waves, z=3, XCD-chunked remap, XOR-swizzled LDS.
// T4 pipeline: raw s_barrier + COUNTED vmcnt. Per iter: glds B(t+1) [2] then
// A-loads(t+2) [4] issued before MFMA(t); cvt A(t+1) waits vmcnt(6) (compiler);
// pre-barrier asm vmcnt(4) drains only B(t+1) — A(t+2) stays in flight ACROSS
// the barrier (depth-2 A prefetch, ~1 full iter of latency cover).
struct ProjArgs {
  const float* A[3];
  const ushort_t* B[3];
  ushort_t* C[3];
};

__global__ __launch_bounds__(256) void gemm_proj(ProjArgs pa, int M, int N) {
  constexpr int K = 1024;
  constexpr int NT = K / 32;  // 32
  __shared__ __align__(16) ushort_t Al[2][128][32];
  __shared__ __align__(16) ushort_t Bl[2][128][32];
  const int orig = blockIdx.x + (blockIdx.y << 3) + (blockIdx.z << 8);
  const int swz = (orig & 7) * 96 + (orig >> 3);
  const int bn = (swz & 7) * 128;
  const int bm = ((swz >> 3) & 31) * 128;
  const int z = swz >> 8;
  const float* A = pa.A[z];
  const ushort_t* B = pa.B[z];
  ushort_t* C = pa.C[z];
  const int tid = threadIdx.x;
  const int w = tid >> 6, lane = tid & 63;
  const int l15 = lane & 15, lhi = lane >> 4;
  const int wm = (w >> 1) * 64, wn = (w & 1) * 64;

  float4v zero4 = {0.f, 0.f, 0.f, 0.f};
  float4v acc[4][4];
  for (int i = 0; i < 4; i++)
    for (int j = 0; j < 4; j++) acc[i][j] = zero4;

  const int sr = tid >> 2;
  const int sc = tid & 3;
  const int ssw = sc ^ ((sr >> 1) & 3);
  const ushort_t* gb = B + (size_t)(bn + sr) * K + ssw * 8;
  const float* gaf = A + (size_t)(bm + sr) * K + sc * 8;
  char* lBb = (char*)&Bl[0][0][0];
  const int wb = w * 1024;
  const int rsw8 = (lhi ^ ((l15 >> 1) & 3)) * 8;

  // Two named A-register sets (rule #20: static indexing only).
  float4v e00, e01, e10, e11;  // set E
  float4v o00, o01, o10, o11;  // set O

#define LOADA(d00, d01, d10, d11, KT)          \
  do {                                         \
    const float* p0 = gaf + (KT);              \
    d00 = ((const float4v*)p0)[0];             \
    d01 = ((const float4v*)p0)[1];             \
    const float* p1 = gaf + (size_t)64 * K + (KT); \
    d10 = ((const float4v*)p1)[0];             \
    d11 = ((const float4v*)p1)[1];             \
  } while (0)

#define STOREA(BUF, s00, s01, s10, s11)                   \
  do {                                                    \
    *(short8*)&Al[BUF][sr][ssw * 8] = cvt8(s00, s01);     \
    *(short8*)&Al[BUF][64 + sr][ssw * 8] = cvt8(s10, s11); \
  } while (0)

#define GLDSB(BUF, KT)                                           \
  do {                                                           \
    glds16(gb + (KT), lBb + (BUF)*8192 + wb);                    \
    glds16(gb + (size_t)64 * K + (KT), lBb + (BUF)*8192 + 4096 + wb); \
  } while (0)

#define MFMAS(BUF)                                                        \
  do {                                                                    \
    short8 af[4], bfr[4];                                                 \
    _Pragma("unroll") for (int mi = 0; mi < 4; mi++)                      \
        af[mi] = *(const short8*)&Al[BUF][wm + mi * 16 + l15][rsw8];      \
    _Pragma("unroll") for (int ni = 0; ni < 4; ni++)                      \
        bfr[ni] = *(const short8*)&Bl[BUF][wn + ni * 16 + l15][rsw8];     \
    _Pragma("unroll") for (int mi = 0; mi < 4; mi++)                      \
        _Pragma("unroll") for (int ni = 0; ni < 4; ni++) acc[mi][ni] =    \
        __builtin_amdgcn_mfma_f32_16x16x32_bf16(af[mi], bfr[ni],          \
                                                acc[mi][ni], 0, 0, 0);    \
  } while (0)

#define BAR(N_IMM)                                                     \
  do {                                                                 \
    asm volatile("s_waitcnt vmcnt(" #N_IMM ") lgkmcnt(0)" ::: "memory"); \
    __builtin_amdgcn_s_barrier();                                      \
    __builtin_amdgcn_sched_barrier(0);                                 \
  } while (0)

  // Prologue: A(0)->E->bufA0; B(0)->bufB0; A(1)->O in flight across barrier.
  LOADA(e00, e01, e10, e11, 0);         // [E4]
  GLDSB(0, 0);                          // [E4,B2]
  LOADA(o00, o01, o10, o11, 32);        // [E4,B2,O4]
  STOREA(0, e00, e01, e10, e11);        // compiler waits E: vmcnt(6)
  BAR(4);                               // B(0) done; O4 in flight

  // Main loop: t = 0..NT-3, two statically-unrolled bodies (parity).
  for (int t = 0; t < NT - 2; t += 2) {
    // even body: compute buf0 (tile t), cur=O=A(t+1), next=E=A(t+2)
    GLDSB(1, (t + 1) * 32);                    // [O4,B2]
    LOADA(e00, e01, e10, e11, (t + 2) * 32);   // [O4,B2,E4]
    MFMAS(0);
    STOREA(1, o00, o01, o10, o11);             // waits O: vmcnt(6)
    BAR(4);                                    // B done; E4 across barrier
    // odd body: compute buf1 (tile t+1), cur=E=A(t+2), next=O=A(t+3)
    GLDSB(0, (t + 2) * 32);                    // [E4,B2]
    LOADA(o00, o01, o10, o11, (t + 3) * 32);   // [E4,B2,O4]
    MFMAS(1);
    STOREA(0, e00, e01, e10, e11);             // waits E: vmcnt(6)
    BAR(4);                                    // B done; O4 across barrier
  }

  // Peeled t = NT-2 (buf0; cur=O=A(NT-1); no next-A)
  GLDSB(1, (NT - 1) * 32);          // [O4,B2]
  MFMAS(0);
  STOREA(1, o00, o01, o10, o11);    // waits O: vmcnt(2)
  BAR(0);                           // drain B(NT-1)
  // Peeled t = NT-1 (buf1; no staging, no barrier)
  MFMAS(1);

#undef LOADA
#undef STOREA
#undef GLDSB
#undef MFMAS
#undef BAR

#pragma unroll
  for (int mi = 0; mi < 4; mi++)
#pragma unroll
    for (int ni = 0; ni < 4; ni++)
#pragma unroll
      for (int i = 0; i < 4; i++) {
        int row = bm + wm + mi * 16 + lhi * 4 + i;
        int col = bn + wn + ni * 16 + l15;
        C[(size_t)row * N + col] = f2bf(acc[mi][ni][i]);
      }
}

// ---------------- output GEMM: C_f32 = A_bf16 * B_bf16^T -------------------
// Round-9 structure unchanged (measured-stable; not the top cost).
__global__ __launch_bounds__(256) void gemm_out(const ushort_t* __restrict__ A,
                                                const ushort_t* __restrict__ B,
                                                float* __restrict__ Cout, int M,
                                                int N, int K) {
  __shared__ __align__(16) ushort_t Al[2][128][32];
  __shared__ __align__(16) ushort_t Bl[2][128][32];
  const int orig = blockIdx.x + (blockIdx.y << 3);
  const int swz = (orig & 7) * 32 + (orig >> 3);
  const int bn = (swz & 7) * 128;
  const int bm = (swz >> 3) * 128;
  const int tid = threadIdx.x;
  const int w = tid >> 6, lane = tid & 63;
  const int l15 = lane & 15, lhi = lane >> 4;
  const int wm = (w >> 1) * 64, wn = (w & 1) * 64;

  float4v zero4 = {0.f, 0.f, 0.f, 0.f};
  float4v acc[4][4];
  for (int i = 0; i < 4; i++)
    for (int j = 0; j < 4; j++) acc[i][j] = zero4;

  const int sr = tid >> 2;
  const int sc = tid & 3;
  const int ssw = sc ^ ((sr >> 1) & 3);
  const ushort_t* ga = A + (size_t)(bm + sr) * K + ssw * 8;
  const ushort_t* gb = B + (size_t)(bn + sr) * K + ssw * 8;
  char* lAb = (char*)&Al[0][0][0];
  char* lBb = (char*)&Bl[0][0][0];
  const int wb = w * 1024;
  const int rsw8 = (lhi ^ ((l15 >> 1) & 3)) * 8;
  const int NT = K / 32;

  glds16(ga, lAb + wb);
  glds16(ga + (size_t)64 * K, lAb + 4096 + wb);
  glds16(gb, lBb + wb);
  glds16(gb + (size_t)64 * K, lBb + 4096 + wb);
  __syncthreads();

  int cur = 0;
  for (int t = 0; t < NT; ++t) {
    const int ktn = (t + 1) * 32;
    if (t + 1 < NT) {
      char* lAn = lAb + (cur ^ 1) * 8192;
      char* lBn = lBb + (cur ^ 1) * 8192;
      glds16(ga + ktn, lAn + wb);
      glds16(ga + (size_t)64 * K + ktn, lAn + 4096 + wb);
      glds16(gb + ktn, lBn + wb);
      glds16(gb + (size_t)64 * K + ktn, lBn + 4096 + wb);
    }
    short8 af[4], bfr[4];
#pragma unroll
    for (int mi = 0; mi < 4; mi++)
      af[mi] = *(const short8*)&Al[cur][wm + mi * 16 + l15][rsw8];
#pragma unroll
    for (int ni = 0; ni < 4; ni++)
      bfr[ni] = *(const short8*)&Bl[cur][wn + ni * 16 + l15][rsw8];
#pragma unroll
    for (int mi = 0; mi < 4; mi++)
#pragma unroll
      for (int ni = 0; ni < 4; ni++)
        acc[mi][ni] = __builtin_amdgcn_mfma_f32_16x16x32_bf16(
            af[mi], bfr[ni], acc[mi][ni], 0, 0, 0);
    __syncthreads();
    cur ^= 1;
  }

#pragma unroll
  for (int mi = 0; mi < 4; mi++)
#pragma unroll
    for (int ni = 0; ni < 4; ni++)
#pragma unroll
      for (int i = 0; i < 4; i++) {
        int row = bm + wm + mi * 16 + lhi * 4 + i;
        int col = bn + wn + ni * 16 + l15;
        Cout[(size_t)row * N + col] = acc[mi][ni][i];
      }
}

// ---------------- V transpose: Vp[4096][1024] -> Vt[b][h][dd=64][s=1024] ----
__global__ __launch_bounds__(256) void transpose_v_kernel(
    const ushort_t* __restrict__ Vp, ushort_t* __restrict__ Vt) {
  __shared__ ushort_t tile[64][65];
  const int bx = blockIdx.x;  // b*256 + h*16 + c
  const int b = bx >> 8, h = (bx >> 4) & 15, c = bx & 15;
  const int t = threadIdx.x;
#pragma unroll
  for (int i = 0; i < 16; i++) {
    int id = i * 256 + t;
    int tok = id >> 6, dd = id & 63;
    tile[tok][dd] = Vp[(size_t)(b * 1024 + c * 64 + tok) * 1024 + h * 64 + dd];
  }
  __syncthreads();
#pragma unroll
  for (int i = 0; i < 16; i++) {
    int id = i * 256 + t;
    int dd = id >> 6, tok = id & 63;
    Vt[(size_t)((b * 16 + h) * 64 + dd) * 1024 + c * 64 + tok] = tile[tok][dd];
  }
}

// ---------------- flash attention: 1-wave blocks, no barriers --------------
// grid 4096 = b(4) x h(16) x qtile(64 of 16 rows). 64 threads.
__global__ __launch_bounds__(64) void attn_kernel(
    const ushort_t* __restrict__ Qp, const ushort_t* __restrict__ Kp,
    const ushort_t* __restrict__ Vt, const int* __restrict__ valid_lens,
    ushort_t* __restrict__ Ob) {
  __shared__ __align__(16) ushort_t Plds[16][72];
  const int lane = threadIdx.x & 63;
  const int l15 = lane & 15, lhi = lane >> 4;
  const int bx = blockIdx.x;
  const int b = bx >> 10;
  const int h = (bx >> 6) & 15;
  const int qt = bx & 63;
  const int qrow0 = qt * 16;
  const int vlen = valid_lens[b];

  short8 qf0, qf1;
  {
    const ushort_t* qp =
        Qp + (size_t)(b * 1024 + qrow0 + l15) * 1024 + h * 64 + lhi * 8;
    qf0 = *(const short8*)qp;
    qf1 = *(const short8*)(qp + 32);
  }
  float4v zero4 = {0.f, 0.f, 0.f, 0.f};
  float4v o[4] = {zero4, zero4, zero4, zero4};
  float m_i[4] = {NEG_INF, NEG_INF, NEG_INF, NEG_INF};
  float l_i[4] = {0.f, 0.f, 0.f, 0.f};

  const ushort_t* kh = Kp + (size_t)b * 1024 * 1024 + h * 64;
  const ushort_t* vh = Vt + (size_t)(b * 16 + h) * 64 * 1024;

  for (int kt = 0; kt < 16; kt++) {
    const int k0 = kt * 64;
    if (k0 >= vlen) break;  // uniform per wave (same b)

    float4v s[4];
#pragma unroll
    for (int n = 0; n < 4; n++) {
      const ushort_t* kp = kh + (size_t)(k0 + n * 16 + l15) * 1024 + lhi * 8;
      short8 kf0 = *(const short8*)kp;
      short8 kf1 = *(const short8*)(kp + 32);
      s[n] = __builtin_amdgcn_mfma_f32_16x16x32_bf16(qf0, kf0, zero4, 0, 0, 0);
      s[n] = __builtin_amdgcn_mfma_f32_16x16x32_bf16(qf1, kf1, s[n], 0, 0, 0);
    }
    float pm[4] = {NEG_INF, NEG_INF, NEG_INF, NEG_INF};
#pragma unroll
    for (int n = 0; n < 4; n++) {
      const bool ok = (k0 + n * 16 + l15) < vlen;
#pragma unroll
      for (int i = 0; i < 4; i++) {
        float v = s[n][i] * 0.125f;
        v = ok ? v : -1e6f;
        s[n][i] = v;
        pm[i] = fmaxf(pm[i], v);
      }
    }
#pragma unroll
    for (int d = 1; d < 16; d <<= 1)
#pragma unroll
      for (int i = 0; i < 4; i++) pm[i] = fmaxf(pm[i], __shfl_xor(pm[i], d, 64));

    float alpha[4], rs[4];
#pragma unroll
    for (int i = 0; i < 4; i++) {
      float mn = fmaxf(m_i[i], pm[i]);
      alpha[i] = __expf(m_i[i] - mn);
      m_i[i] = mn;
      rs[i] = 0.f;
    }
#pragma unroll
    for (int n = 0; n < 4; n++)
#pragma unroll
      for (int i = 0; i < 4; i++) {
        float p = __expf(s[n][i] - m_i[i]);
        s[n][i] = p;
        rs[i] += p;
      }
#pragma unroll
    for (int d = 1; d < 16; d <<= 1)
#pragma unroll
      for (int i = 0; i < 4; i++) rs[i] += __shfl_xor(rs[i], d, 64);
#pragma unroll
    for (int i = 0; i < 4; i++) l_i[i] = l_i[i] * alpha[i] + rs[i];
#pragma unroll
    for (int n = 0; n < 4; n++)
#pragma unroll
      for (int i = 0; i < 4; i++) o[n][i] *= alpha[i];

    // P (C/D layout) -> LDS -> A-frag layout (wave-private; no barrier needed)
#pragma unroll
    for (int n = 0; n < 4; n++)
#pragma unroll
      for (int i = 0; i < 4; i++)
        Plds[lhi * 4 + i][n * 16 + l15] = f2bf(s[n][i]);

#pragma unroll
    for (int c = 0; c < 2; c++) {
      short8 pa = *(const short8*)&Plds[l15][c * 32 + lhi * 8];
      const ushort_t* vb = vh + k0 + c * 32 + lhi * 8;
#pragma unroll
      for (int n = 0; n < 4; n++) {
        short8 vf = *(const short8*)(vb + (size_t)(n * 16 + l15) * 1024);
        o[n] = __builtin_amdgcn_mfma_f32_16x16x32_bf16(pa, vf, o[n], 0, 0, 0);
      }
    }
  }

#pragma unroll
  for (int n = 0; n < 4; n++)
#pragma unroll
    for (int i = 0; i < 4; i++) {
      float vout = o[n][i] / l_i[i];
      Ob[(size_t)(b * 1024 + qrow0 + lhi * 4 + i) * 1024 + h * 64 + n * 16 +
         l15] = f2bf(vout);
    }
}

// ---------------- host launch ----------------
extern "C" void kernel_launch(void* const* d_in, const int* in_sizes, int n_in,
                              void* d_out, int out_size, void* d_ws,
                              size_t ws_size, hipStream_t stream) {
  (void)in_sizes;
  (void)n_in;
  (void)out_size;
  (void)ws_size;
  const float* q = (const float*)d_in[0];
  const float* k = (const float*)d_in[1];
  const float* v = (const float*)d_in[2];
  const int* vl = (const int*)d_in[3];
  const float* Wq = (const float*)d_in[4];
  const float* Wk = (const float*)d_in[5];
  const float* Wv = (const float*)d_in[6];
  const float* Wo = (const float*)d_in[7];
  float* out = (float*)d_out;
  char* ws = (char*)d_ws;
  const size_t MB = 1u << 20;

  // layout (40 MB): weights bf16 [0,8), Qp [8,16), Kp [16,24), Vp [24,32),
  // Vt [32,40), Ob aliases Vp (dead after transpose).
  ushort_t* wqb = (ushort_t*)(ws + 0 * MB);
  ushort_t* wkb = (ushort_t*)(ws + 2 * MB);
  ushort_t* wvb = (ushort_t*)(ws + 4 * MB);
  ushort_t* wob = (ushort_t*)(ws + 6 * MB);
  ushort_t* Qp = (ushort_t*)(ws + 8 * MB);
  ushort_t* Kp = (ushort_t*)(ws + 16 * MB);
  ushort_t* Vp = (ushort_t*)(ws + 24 * MB);
  ushort_t* Vtp = (ushort_t*)(ws + 32 * MB);
  ushort_t* Ob = Vp;

  CvtW cw;
  cw.in[0] = Wq;
  cw.in[1] = Wk;
  cw.in[2] = Wv;
  cw.in[3] = Wo;
  cw.out[0] = wqb;
  cw.out[1] = wkb;
  cw.out[2] = wvb;
  cw.out[3] = wob;
  cvt_w_kernel<<<dim3(1024, 4), 256, 0, stream>>>(cw);

  ProjArgs pa;
  pa.A[0] = q;
  pa.A[1] = k;
  pa.A[2] = v;
  pa.B[0] = wqb;
  pa.B[1] = wkb;
  pa.B[2] = wvb;
  pa.C[0] = Qp;
  pa.C[1] = Kp;
  pa.C[2] = Vp;
  gemm_proj<<<dim3(8, 32, 3), 256, 0, stream>>>(pa, 4096, 1024);

  transpose_v_kernel<<<1024, 256, 0, stream>>>(Vp, Vtp);
  attn_kernel<<<4096, 64, 0, stream>>>(Qp, Kp, Vtp, vl, Ob);
  gemm_out<<<dim3(8, 32), 256, 0, stream>>>(Ob, wob, out, 4096, 1024, 1024);
}